// Round 6
// baseline (106.127 us; speedup 1.0000x reference)
//
#include <hip/hip_runtime.h>
#include <math.h>

#define HIDDEN   100
#define NCLASS   4
#define NWORDS   40
#define VOCAB    50000
#define NTHR     640
#define MAXC     32        // chain nodes on the LDS fast path (fixed-seed tree, L ~ 10)
#define MAXCHAIN 200

// ws (fallback only, block-0-private): float xe_g[MAXCHAIN*HIDDEN], then a_g[MAXCHAIN*3*HIDDEN]

__global__ __launch_bounds__(NTHR, 1) void k_all(
    const float* __restrict__ xvals, const int* __restrict__ xidx,
    const int* __restrict__ tree, const int* __restrict__ np_ptr,
    const float* __restrict__ E,
    const float* __restrict__ Wz, const float* __restrict__ bz,
    const float* __restrict__ Wr, const float* __restrict__ br,
    const float* __restrict__ Wh, const float* __restrict__ bh,
    const float* __restrict__ Uz, const float* __restrict__ Ur,
    const float* __restrict__ Uh,
    const float* __restrict__ Wout, const float* __restrict__ bout,
    float* __restrict__ ws, float* __restrict__ out)
{
    __shared__ int chain[MAXCHAIN];
    __shared__ int len_s;
    __shared__ __align__(16) float xe_s[MAXC * HIDDEN];          // 12.8 KB
    __shared__ __align__(16) float a_lds[MAXC * 3 * HIDDEN];     // 38.4 KB
    __shared__ __align__(16) float h0[112], h1[112], zbuf[112], rbuf[112];
    __shared__ float ov[NCLASS];

    const int t    = threadIdx.x;
    const int half = t & 1;
    float* xe_g = ws;                          // [MAXCHAIN*HIDDEN]   (L>MAXC only)
    float* a_g  = ws + MAXCHAIN * HIDDEN;      // [MAXCHAIN*3*HIDDEN] (L>MAXC only)

    // ---- W half-row preload: issue first, latency hides under the chase ----
    float2 wreg[25];
    float  bias = 0.f;
    int row = 0;
    if (t < 600) {
        row = t >> 1;
        int m = row / HIDDEN, ri = row - m * HIDDEN;
        const float* Wm = (m == 0 ? Wz : (m == 1 ? Wr : Wh));
        const float2* w2 = (const float2*)(Wm + ri * HIDDEN + half * 50);
        #pragma unroll
        for (int k = 0; k < 25; ++k) wreg[k] = w2[k];
        if (half == 0) bias = (m == 0 ? bz : (m == 1 ? br : bh))[ri];
    }

    // ---- chase ancestor chain of node npar-1 (serial, L2-warm after replay 1) ----
    if (t == 0) {
        int npar = np_ptr[0];
        int len = 0, i = npar - 1; if (i < 0) i = 0;
        while (i > 0 && len < MAXCHAIN - 1) { chain[len++] = i; i = tree[2 * i]; }
        chain[len++] = i;                      // node 0 (zero parent state)
        len_s = len;
    }
    __syncthreads();
    const int L = len_s;

    // ---- gather: xe[d][h] = sum_w val[w] * E[h, idx[w]] ----
    // task u = d*400 + h*4 + wg ; quad shfl reduce, ~10 ILP scattered loads/task
    const int ntask = L * 4 * HIDDEN;
    for (int u = t; u < ntask; u += NTHR) {
        int d   = u / (4 * HIDDEN);
        int rem = u - d * 4 * HIDDEN;
        int h = rem >> 2, wg = rem & 3;
        int c = chain[d];
        const int*   ixp = xidx  + (size_t)c * NWORDS + wg * 10;
        const float* vp  = xvals + (size_t)c * NWORDS + wg * 10;
        int ix[10]; float vv[10];
        #pragma unroll
        for (int w = 0; w < 10; ++w) ix[w] = ixp[w];
        #pragma unroll
        for (int w = 0; w < 10; ++w) vv[w] = vp[w];
        const float* Eh = E + (size_t)h * VOCAB;
        float s0 = 0.f, s1 = 0.f;
        #pragma unroll
        for (int w = 0; w < 10; ++w) {
            float p = vv[w] * Eh[ix[w]];
            if (w & 1) s1 += p; else s0 += p;
        }
        float p = s0 + s1;
        p += __shfl_xor(p, 1);
        p += __shfl_xor(p, 2);
        if (wg == 0) {
            if (d < MAXC) xe_s[d * HIDDEN + h] = p;
            else          xe_g[d * HIDDEN + h] = p;
        }
    }
    __syncthreads();

    // ---- a[d][row] = b[row] + W[row,:] . xe[d]  (thread owns a half-row, all d) ----
    if (t < 600) {
        for (int d = 0; d < L; ++d) {
            const float2* x2 = (const float2*)(((d < MAXC) ? (xe_s + d * HIDDEN)
                                                           : (xe_g + d * HIDDEN)) + half * 50);
            float a0 = 0.f, a1 = 0.f;
            #pragma unroll
            for (int k = 0; k < 25; ++k) {
                float2 w = wreg[k], x = x2[k];
                a0 += w.x * x.x; a1 += w.y * x.y;
            }
            float p = a0 + a1;
            p += __shfl_xor(p, 1);
            if (half == 0) {
                float v = p + bias;
                if (d < MAXC) a_lds[d * 3 * HIDDEN + row] = v;
                else          a_g [d * 3 * HIDDEN + row] = v;
            }
        }
    }

    // ---- U half-row preload (after W's last use: keeps peak VGPR ~130) ----
    float2 ureg[25];
    int grow = 0;
    if (t < 600) {
        grow = (t < 400) ? (t >> 1) : (200 + ((t - 400) >> 1));
        int m = grow / HIDDEN, ri = grow - m * HIDDEN;
        const float* Um = (m == 0 ? Uz : (m == 1 ? Ur : Uh));
        const float2* u2 = (const float2*)(Um + ri * HIDDEN + half * 50);
        #pragma unroll
        for (int k = 0; k < 25; ++k) ureg[k] = u2[k];
    }
    if (t < 112) { h0[t] = 0.f; h1[t] = 0.f; }
    __syncthreads();

    // ---- GRU recurrence over the chain, root-first ----
    float* hc = h0;
    float* hn = h1;
    for (int d = L - 1; d >= 0; --d) {
        const float* ad = (d < MAXC) ? (a_lds + d * 3 * HIDDEN) : (a_g + d * 3 * HIDDEN);
        if (t < 400) {                          // z and r rows (0..199)
            const float2* h2 = (const float2*)(hc + half * 50);  // 2-addr broadcast
            float a0 = 0.f, a1 = 0.f;
            #pragma unroll
            for (int k = 0; k < 25; ++k) {
                float2 u = ureg[k], x = h2[k];
                a0 += u.x * x.x; a1 += u.y * x.y;
            }
            float p = a0 + a1;
            p += __shfl_xor(p, 1);
            if (half == 0) {
                float v = fminf(fmaxf(ad[grow] + p, 0.f), 1.f);  // Hardtanh(0,1)
                if (grow < HIDDEN) zbuf[grow] = v;                          // z
                else               rbuf[grow - HIDDEN] = v * hc[grow - HIDDEN]; // r*h
            }
        }
        __syncthreads();
        if (t >= 400 && t < 600) {              // c rows (200..299) + state update
            const float2* r2 = (const float2*)(rbuf + half * 50);
            float a0 = 0.f, a1 = 0.f;
            #pragma unroll
            for (int k = 0; k < 25; ++k) {
                float2 u = ureg[k], x = r2[k];
                a0 += u.x * x.x; a1 += u.y * x.y;
            }
            float p = a0 + a1;
            p += __shfl_xor(p, 1);
            if (half == 0) {
                int i = grow - 200;
                float c = tanhf(ad[grow] + p);
                float z = zbuf[i];
                hn[i] = (1.f - z) * hc[i] + z * c;
            }
        }
        __syncthreads();
        float* tmp = hc; hc = hn; hn = tmp;
    }

    // ---- out = softmax(W_out @ h + b_out) ----
    if (t < NCLASS) {
        float acc = bout[t];
        const float* wr = Wout + t * HIDDEN;
        for (int j = 0; j < HIDDEN; ++j) acc += wr[j] * hc[j];
        ov[t] = acc;
    }
    __syncthreads();
    if (t == 0) {
        float mx = fmaxf(fmaxf(ov[0], ov[1]), fmaxf(ov[2], ov[3]));
        float e0 = expf(ov[0] - mx), e1 = expf(ov[1] - mx);
        float e2 = expf(ov[2] - mx), e3 = expf(ov[3] - mx);
        float s = e0 + e1 + e2 + e3;
        out[0] = e0 / s; out[1] = e1 / s; out[2] = e2 / s; out[3] = e3 / s;
    }
}

extern "C" void kernel_launch(void* const* d_in, const int* in_sizes, int n_in,
                              void* d_out, int out_size, void* d_ws, size_t ws_size,
                              hipStream_t stream) {
    const float* xvals = (const float*)d_in[0];
    const int*   xidx  = (const int*)d_in[1];
    const int*   tree  = (const int*)d_in[2];
    const int*   npar  = (const int*)d_in[3];
    const float* E     = (const float*)d_in[4];
    const float* Wz    = (const float*)d_in[5];
    const float* Uz    = (const float*)d_in[6];
    const float* bz    = (const float*)d_in[7];
    const float* Wr    = (const float*)d_in[8];
    const float* Ur    = (const float*)d_in[9];
    const float* br    = (const float*)d_in[10];
    const float* Wh    = (const float*)d_in[11];
    const float* Uh    = (const float*)d_in[12];
    const float* bh    = (const float*)d_in[13];
    const float* Wout  = (const float*)d_in[14];
    const float* bout  = (const float*)d_in[15];

    k_all<<<1, NTHR, 0, stream>>>(xvals, xidx, tree, npar, E,
                                  Wz, bz, Wr, br, Wh, bh,
                                  Uz, Ur, Uh, Wout, bout,
                                  (float*)d_ws, (float*)d_out);
}

// Round 7
// 28.708 us; speedup vs baseline: 3.6968x; 3.6968x over previous
//
#include <hip/hip_runtime.h>
#include <math.h>

#define HIDDEN   100
#define NCLASS   4
#define NWORDS   40
#define VOCAB    50000
#define PCAP     5120
#define MAXC     24        // chain nodes of a[] staged in GRU LDS (L expected ~10)
#define MAXCHAIN 200
#define NTHR     640
#define PREP_BLKS 48
#define HH       (HIDDEN * HIDDEN)

// ws layout: byte 0: int len; byte 64: float a[MAXCHAIN][3*HIDDEN]

__global__ __launch_bounds__(NTHR) void k_prep(
    const float* __restrict__ xvals, const int* __restrict__ xidx,
    const int* __restrict__ tree, const int* __restrict__ np_ptr,
    const float* __restrict__ E,
    const float* __restrict__ Wz, const float* __restrict__ bz,
    const float* __restrict__ Wr, const float* __restrict__ br,
    const float* __restrict__ Wh, const float* __restrict__ bh,
    const float* __restrict__ Uz, const float* __restrict__ Ur,
    const float* __restrict__ Uh, const float* __restrict__ Wout,
    int* __restrict__ len_out, float* __restrict__ a)
{
    __shared__ int P[PCAP];
    __shared__ int chain[MAXCHAIN];
    __shared__ int len_s;
    __shared__ __align__(16) float xe[HIDDEN + 4];

    const int t = threadIdx.x;
    const int npar = np_ptr[0];
    const int pcap = (npar < PCAP) ? npar : PCAP;

    // W half-row preload: 25 independent float2 loads, latency hides under staging+chase
    float2 wreg[25];
    float bias = 0.f;
    int row = 0, half = t & 1;
    if (t < 600) {
        row = t >> 1;
        int m = row / HIDDEN, ri = row - m * HIDDEN;
        const float* Wm = (m == 0 ? Wz : (m == 1 ? Wr : Wh));
        const float2* w2 = (const float2*)(Wm + ri * HIDDEN + half * 50);
        #pragma unroll
        for (int k = 0; k < 25; ++k) wreg[k] = w2[k];
        if (half == 0) bias = (m == 0 ? bz : (m == 1 ? br : bh))[ri];
    }

    // parents -> LDS, chase ancestor chain of node npar-1 (every block)
    for (int i = t; i < pcap; i += NTHR) P[i] = tree[2 * i];
    __syncthreads();
    if (t == 0) {
        int len = 0, i = npar - 1; if (i < 0) i = 0;
        while (i > 0 && len < MAXCHAIN - 1) { chain[len++] = i; i = (i < pcap) ? P[i] : tree[2 * i]; }
        chain[len++] = i;                       // node 0 (zero parent state)
        len_s = len;
        if (blockIdx.x == 0) *len_out = len;
    }
    __syncthreads();
    const int L = len_s;

    if ((int)blockIdx.x >= L) {
        // idle blocks: warm U_z/U_r/U_h + W_out into L3 so k_gru's preload hits cache.
        // Results sunk, never stored -> cannot affect correctness.
        float sink = 0.f;
        int wb = blockIdx.x - L;
        int nw = PREP_BLKS - L; if (nw < 1) nw = 1;
        const int total = 3 * HH + NCLASS * HIDDEN;
        for (int j = wb * NTHR + t; j < total; j += nw * NTHR) {
            const float* p;
            if      (j <     HH) p = Uz   + j;
            else if (j < 2 * HH) p = Ur   + j -     HH;
            else if (j < 3 * HH) p = Uh   + j - 2 * HH;
            else                 p = Wout + j - 3 * HH;
            sink += *p;
        }
        asm volatile("" :: "v"(sink));          // keep loads live (rule #17)
        return;
    }

    for (int d = blockIdx.x; d < L; d += gridDim.x) {
        const int c = chain[d];
        // xe[h] = sum_w val[w] * E[h, idx[w]] : 400 units, quad shfl reduce
        if (t < 4 * HIDDEN) {
            int h = t >> 2, wg = t & 3;
            const int*   ixp = xidx  + (size_t)c * NWORDS + wg * 10;
            const float* vp  = xvals + (size_t)c * NWORDS + wg * 10;
            int ix[10]; float vv[10];
            #pragma unroll
            for (int w = 0; w < 10; ++w) ix[w] = ixp[w];
            #pragma unroll
            for (int w = 0; w < 10; ++w) vv[w] = vp[w];
            const float* Eh = E + (size_t)h * VOCAB;
            float s0 = 0.f, s1 = 0.f;
            #pragma unroll
            for (int w = 0; w < 10; ++w) {
                float p = vv[w] * Eh[ix[w]];
                if (w & 1) s1 += p; else s0 += p;
            }
            float p = s0 + s1;
            p += __shfl_xor(p, 1);
            p += __shfl_xor(p, 2);
            if (wg == 0) xe[h] = p;
        }
        __syncthreads();
        // a[d][row] = b[row] + W[row,:] . xe  : 600 half-row units
        if (t < 600) {
            const float2* x2 = (const float2*)(xe + half * 50);
            float a0 = 0.f, a1 = 0.f;
            #pragma unroll
            for (int k = 0; k < 25; ++k) {
                float2 w = wreg[k], x = x2[k];
                a0 += w.x * x.x; a1 += w.y * x.y;
            }
            float p = a0 + a1;
            p += __shfl_xor(p, 1);
            if (half == 0) a[d * 3 * HIDDEN + row] = p + bias;
        }
        __syncthreads();
    }
}

__global__ __launch_bounds__(NTHR) void k_gru(
    const float* __restrict__ Uz, const float* __restrict__ Ur,
    const float* __restrict__ Uh,
    const float* __restrict__ Wout, const float* __restrict__ bout,
    const int* __restrict__ len_p, const float* __restrict__ a,
    float* __restrict__ out)
{
    __shared__ __align__(16) float a_lds[MAXC * 3 * HIDDEN];   // 28.8 KB
    __shared__ __align__(16) float h0[112], h1[112], zbuf[112], rbuf[112];
    __shared__ float ov[NCLASS];

    const int t = threadIdx.x;
    const int half = t & 1;

    // U half-row preload (independent, issue first; L3-warm thanks to k_prep helpers)
    // rows: t<400 -> rows 0..199 (U_z,U_r); 400<=t<600 -> rows 200..299 (U_h)
    float2 ureg[25];
    int grow = 0;
    if (t < 600) {
        grow = (t < 400) ? (t >> 1) : (200 + ((t - 400) >> 1));
        int m = grow / HIDDEN, ri = grow - m * HIDDEN;
        const float* Um = (m == 0 ? Uz : (m == 1 ? Ur : Uh));
        const float2* u2 = (const float2*)(Um + ri * HIDDEN + half * 50);
        #pragma unroll
        for (int k = 0; k < 25; ++k) ureg[k] = u2[k];
    }
    // optimistic batched prefetch of a[0..MAXC*300) (beyond L*300 is unread garbage)
    float ar[12];
    #pragma unroll
    for (int j = 0; j < 12; ++j) {
        int k = t + j * NTHR;
        if (k < MAXC * 3 * HIDDEN) ar[j] = a[k];
    }
    const int L = *len_p;
    #pragma unroll
    for (int j = 0; j < 12; ++j) {
        int k = t + j * NTHR;
        if (k < MAXC * 3 * HIDDEN) a_lds[k] = ar[j];
    }
    if (t < 112) { h0[t] = 0.f; h1[t] = 0.f; }
    __syncthreads();

    float* hc = h0;
    float* hn = h1;
    for (int d = L - 1; d >= 0; --d) {
        const float* ad = (d < MAXC) ? (a_lds + d * 3 * HIDDEN) : (a + d * 3 * HIDDEN);
        if (t < 400) {                           // z and r rows (0..199)
            const float2* h2 = (const float2*)(hc + half * 50);   // 2-addr broadcast, conflict-free
            float a0 = 0.f, a1 = 0.f;
            #pragma unroll
            for (int k = 0; k < 25; ++k) {
                float2 u = ureg[k], x = h2[k];
                a0 += u.x * x.x; a1 += u.y * x.y;
            }
            float p = a0 + a1;
            p += __shfl_xor(p, 1);
            if (half == 0) {
                float v = fminf(fmaxf(ad[grow] + p, 0.f), 1.f);   // Hardtanh(0,1)
                if (grow < HIDDEN) zbuf[grow] = v;                // z
                else               rbuf[grow - HIDDEN] = v * hc[grow - HIDDEN]; // r*h
            }
        }
        __syncthreads();
        if (t >= 400 && t < 600) {               // c rows (200..299) + state update
            const float2* r2 = (const float2*)(rbuf + half * 50);
            float a0 = 0.f, a1 = 0.f;
            #pragma unroll
            for (int k = 0; k < 25; ++k) {
                float2 u = ureg[k], x = r2[k];
                a0 += u.x * x.x; a1 += u.y * x.y;
            }
            float p = a0 + a1;
            p += __shfl_xor(p, 1);
            if (half == 0) {
                int i = grow - 200;
                float c = tanhf(ad[grow] + p);
                float z = zbuf[i];
                hn[i] = (1.f - z) * hc[i] + z * c;
            }
        }
        __syncthreads();
        float* tmp = hc; hc = hn; hn = tmp;
    }

    if (t < NCLASS) {
        float acc = bout[t];
        const float* wr = Wout + t * HIDDEN;
        for (int j = 0; j < HIDDEN; ++j) acc += wr[j] * hc[j];
        ov[t] = acc;
    }
    __syncthreads();
    if (t == 0) {
        float mx = fmaxf(fmaxf(ov[0], ov[1]), fmaxf(ov[2], ov[3]));
        float e0 = expf(ov[0] - mx), e1 = expf(ov[1] - mx);
        float e2 = expf(ov[2] - mx), e3 = expf(ov[3] - mx);
        float s = e0 + e1 + e2 + e3;
        out[0] = e0 / s; out[1] = e1 / s; out[2] = e2 / s; out[3] = e3 / s;
    }
}

extern "C" void kernel_launch(void* const* d_in, const int* in_sizes, int n_in,
                              void* d_out, int out_size, void* d_ws, size_t ws_size,
                              hipStream_t stream) {
    const float* xvals = (const float*)d_in[0];
    const int*   xidx  = (const int*)d_in[1];
    const int*   tree  = (const int*)d_in[2];
    const int*   npar  = (const int*)d_in[3];
    const float* E     = (const float*)d_in[4];
    const float* Wz    = (const float*)d_in[5];
    const float* Uz    = (const float*)d_in[6];
    const float* bz    = (const float*)d_in[7];
    const float* Wr    = (const float*)d_in[8];
    const float* Ur    = (const float*)d_in[9];
    const float* br    = (const float*)d_in[10];
    const float* Wh    = (const float*)d_in[11];
    const float* Uh    = (const float*)d_in[12];
    const float* bh    = (const float*)d_in[13];
    const float* Wout  = (const float*)d_in[14];
    const float* bout  = (const float*)d_in[15];

    int*   len = (int*)d_ws;
    float* a   = (float*)((char*)d_ws + 64);

    k_prep<<<PREP_BLKS, NTHR, 0, stream>>>(xvals, xidx, tree, npar, E,
                                           Wz, bz, Wr, br, Wh, bh,
                                           Uz, Ur, Uh, Wout, len, a);
    k_gru<<<1, NTHR, 0, stream>>>(Uz, Ur, Uh, Wout, bout, len, a, (float*)d_out);
}